// Round 12
// baseline (1382.542 us; speedup 1.0000x reference)
//
#include <hip/hip_runtime.h>
#include <math.h>

// VQ quantizer: z [65536, 256] fp32, codebook [1024, 256] fp32.
// Outputs flat: z_q [16777216] | loss [1] | indices [65536] (as float values).
//
// Numerics contract (validated R1..R11, absmax 0.0 — keep bit-identical):
//   A_t = sum(z_t^2)  -- numpy pairwise order (8-acc chains, 128-blocks, fixed tree)
//   B_n = sum(e_n^2)  -- same
//   d   = fl( fl(A+B) - 2*M ),  M = fp32 fma-accumulated dot, k ascending
//   argmin: global first-min == lexicographic min of key (d_bits<<32 | idx)
//   z_q_out = fl( z + fl(e - z) ),  loss = fl(mf + fl(10*mf)), mf=(float)(Σdx²/2^24)
//
// R11 lesson: LDS pipe was the wall (1280 b128 reads/wave x ~12cyc ≈ 983K cyc/CU
// vs 524K FMA cyc) — broadcast reads get no discount. This version: z operands
// wave-uniform -> SGPR scalar loads (no LDS, no VALU); e lane-unique -> 2 LDS
// reads per k4 per wave (10x less LDS traffic), gload_lds double-buffered.
// HARD RULE: never pass a 2nd __launch_bounds__ arg (VGPR=64 pin + GB spills).

#define NTOK     65536
#define DDIM     256
#define NCODE    1024
#define LOSS_OFF 16777216
#define IDX_OFF  16777217

// ws layout: [0] double loss_acc | [64] float wsB[1024] | [8192] u64 keys[65536]
//            | [532480] float wsA[65536]

#define GLOAD_LDS16(gp, lp)                                                       \
    __builtin_amdgcn_global_load_lds(                                             \
        (const __attribute__((address_space(1))) void*)(gp),                      \
        (__attribute__((address_space(3))) void*)(lp), 16, 0, 0)

// ---------------- kernel 0: B_n (numpy-pairwise), zero loss, init argmin keys.
__global__ void vq_prep(const float* __restrict__ cb, float* __restrict__ wsB,
                        double* __restrict__ loss_acc,
                        unsigned long long* __restrict__ keys)
{
#pragma clang fp contract(off)
    int gid = blockIdx.x * blockDim.x + threadIdx.x;
    if (gid == 0) *loss_acc = 0.0;
    unsigned long long* kp = keys + (size_t)gid * 4;
    kp[0] = kp[1] = kp[2] = kp[3] = 0xFFFFFFFFFFFFFFFFull;
    if (gid >= NCODE) return;
    const float* a = cb + gid * DDIM;
    float half[2];
    for (int h = 0; h < 2; ++h) {
        const float* b = a + h * 128;
        float r[8];
#pragma unroll
        for (int j = 0; j < 8; ++j) { float v = b[j]; r[j] = v * v; }
        for (int i = 8; i < 128; i += 8) {
#pragma unroll
            for (int j = 0; j < 8; ++j) { float v = b[i + j]; float s = v * v; r[j] = r[j] + s; }
        }
        half[h] = ((r[0] + r[1]) + (r[2] + r[3])) + ((r[4] + r[5]) + (r[6] + r[7]));
    }
    wsB[gid] = half[0] + half[1];
}

// ---------------- kernel 0b: A_t (numpy-pairwise) for every token.
__global__ void vq_anorm(const float* __restrict__ z, float* __restrict__ wsA)
{
#pragma clang fp contract(off)
    int t = blockIdx.x * blockDim.x + threadIdx.x;
    const float* a = z + (size_t)t * DDIM;
    float half[2];
    for (int h = 0; h < 2; ++h) {
        const float* b = a + h * 128;
        float r[8];
#pragma unroll
        for (int j = 0; j < 8; ++j) { float v = b[j]; r[j] = v * v; }
        for (int i = 8; i < 128; i += 8) {
#pragma unroll
            for (int j = 0; j < 8; ++j) { float v = b[i + j]; float s = v * v; r[j] = r[j] + s; }
        }
        half[h] = ((r[0] + r[1]) + (r[2] + r[3])) + ((r[4] + r[5]) + (r[6] + r[7]));
    }
    wsA[t] = half[0] + half[1];
}

// ---------------- kernel 1: distance GEMM + per-tile argmin -> atomicMin keys.
// Grid 4096 x 512: block b -> xcd = b&7, sl = b>>3, token-tile tt = xcd*64+(sl>>3),
// code-tile ct = sl&7 (siblings of a token-tile share one XCD's L2).
// Wave wv owns 16 tokens (z via wave-uniform SGPR loads); lane L owns codes
// {n0+L, n0+64+L} (e via lane-unique ds_read_b128 from a double-buffered
// [128 codes][32 k] LDS tile staged with global_load_lds).
__global__ __launch_bounds__(512) void vq_main(const float* __restrict__ z,
                                               const float* __restrict__ cb,
                                               const float* __restrict__ wsB,
                                               const float* __restrict__ wsA,
                                               unsigned long long* __restrict__ keys)
{
    __shared__ float es[2][128 * 32];   // 2 x 16 KB double buffer

    const int tid = threadIdx.x;
    const int L = tid & 63;
    const int wv = __builtin_amdgcn_readfirstlane(tid >> 6);   // 0..7, SGPR
    const int b = blockIdx.x;
    const int xcd = b & 7, sl = b >> 3;
    const int tt = xcd * 64 + (sl >> 3);
    const int ct = sl & 7;
    const int t0 = tt * 128;
    const int n0 = ct * 128;

    // wave-uniform z pointer: tokens t0+16*wv .. +15 (scalar-load path)
    const float* zw = z + (size_t)(t0 + 16 * wv) * DDIM;

    // per-lane codebook norms
    const float B0 = wsB[n0 + L];
    const float B1 = wsB[n0 + 64 + L];

    // staging: issue s in {0,1}; lane L sources f4 index f = s*512 + wv*64 + L
    //   -> code row (f>>3), f4 col (f&7); dest = linear LDS float idx f*4.
    const char* cbc = (const char*)cb;
    const long eoffA = (long)(n0 + wv * 8 + (L >> 3)) * 1024 + (L & 7) * 16;
    const long eoffB = (long)(n0 + 64 + wv * 8 + (L >> 3)) * 1024 + (L & 7) * 16;

    float acc[16][2];
#pragma unroll
    for (int i = 0; i < 16; ++i) { acc[i][0] = 0.0f; acc[i][1] = 0.0f; }

    // prologue: stage kc=0 into buffer 0
    GLOAD_LDS16(cbc + eoffA, &es[0][wv * 256]);
    GLOAD_LDS16(cbc + eoffB, &es[0][2048 + wv * 256]);
    __syncthreads();

    int cur = 0;
    for (int kc = 0; kc < 8; ++kc) {
        if (kc < 7) {   // prefetch next k-chunk into the other buffer
            GLOAD_LDS16(cbc + eoffA + (kc + 1) * 128, &es[cur ^ 1][wv * 256]);
            GLOAD_LDS16(cbc + eoffB + (kc + 1) * 128, &es[cur ^ 1][2048 + wv * 256]);
        }
        const float* ep0 = &es[cur][32 * L];          // code n0+L, 32 k-values
        const float* ep1 = &es[cur][2048 + 32 * L];   // code n0+64+L
#pragma unroll
        for (int ks = 0; ks < 8; ++ks) {
            float4 ea = *(const float4*)(ep0 + 4 * ks);
            float4 eb = *(const float4*)(ep1 + 4 * ks);
            const float* zk = zw + (kc * 8 + ks) * 4;
#pragma unroll
            for (int tok = 0; tok < 16; ++tok) {
                float4 zf = *(const float4*)(zk + tok * 256);   // uniform -> s_load
                acc[tok][0] = __builtin_fmaf(zf.x, ea.x, acc[tok][0]);
                acc[tok][0] = __builtin_fmaf(zf.y, ea.y, acc[tok][0]);
                acc[tok][0] = __builtin_fmaf(zf.z, ea.z, acc[tok][0]);
                acc[tok][0] = __builtin_fmaf(zf.w, ea.w, acc[tok][0]);
                acc[tok][1] = __builtin_fmaf(zf.x, eb.x, acc[tok][1]);
                acc[tok][1] = __builtin_fmaf(zf.y, eb.y, acc[tok][1]);
                acc[tok][1] = __builtin_fmaf(zf.z, eb.z, acc[tok][1]);
                acc[tok][1] = __builtin_fmaf(zf.w, eb.w, acc[tok][1]);
            }
        }
        __syncthreads();   // drains prefetch vmcnt + all lanes done with cur
        cur ^= 1;
    }

    // epilogue: d = fl(fl(A+B) - 2*M); global first-min via 64-lane butterfly
    unsigned long long mykey = 0xFFFFFFFFFFFFFFFFull;
#pragma unroll
    for (int tok = 0; tok < 16; ++tok) {
        float A = wsA[t0 + 16 * wv + tok];            // uniform -> scalar load
        float t1a = A + B0;
        float dA = t1a - 2.0f * acc[tok][0];
        float t1b = A + B1;
        float dB = t1b - 2.0f * acc[tok][1];
        float d; int n;
        if (dB < dA) { d = dB; n = n0 + 64 + L; }     // strict: ties keep lower idx
        else         { d = dA; n = n0 + L; }
        for (int off = 1; off < 64; off <<= 1) {
            float od = __shfl_xor(d, off);
            int   on = __shfl_xor(n, off);
            if (od < d || (od == d && on < n)) { d = od; n = on; }
        }
        if (L == tok) mykey = ((unsigned long long)__float_as_uint(d) << 32) |
                              (unsigned int)n;
    }
    if (L < 16) atomicMin(&keys[t0 + 16 * wv + L], mykey);
}

// ---------------- kernel 2: gather z_q, indices, fp64 loss partials.
__global__ __launch_bounds__(256) void vq_gather(const float* __restrict__ z,
                                                 const float* __restrict__ cb,
                                                 const unsigned long long* __restrict__ keys,
                                                 double* __restrict__ loss_acc,
                                                 float* __restrict__ out)
{
    __shared__ double lred[4];
    const int tid = threadIdx.x;
    const int tx = tid & 15, ty = tid >> 4;
    const int t0 = blockIdx.x * 64;

    double ld = 0.0;
#pragma unroll
    for (int i = 0; i < 4; ++i) {
        int t = t0 + ty * 4 + i;
        unsigned long long key = keys[t];
        int w = (int)(unsigned int)(key & 0xFFFFFFFFull);
        const float4* crow = (const float4*)(cb + (size_t)w * DDIM);
        const float4* zrow = (const float4*)(z + (size_t)t * DDIM);
        float4* orow = (float4*)(out + (size_t)t * DDIM);
#pragma unroll
        for (int q = 0; q < 4; ++q) {
            int c4 = tx * 4 + q;
            float4 e4 = crow[c4];
            float4 z4 = zrow[c4];
            float4 o;
            float dx;
            dx = e4.x - z4.x; o.x = z4.x + dx; ld += (double)(dx * dx);
            dx = e4.y - z4.y; o.y = z4.y + dx; ld += (double)(dx * dx);
            dx = e4.z - z4.z; o.z = z4.z + dx; ld += (double)(dx * dx);
            dx = e4.w - z4.w; o.w = z4.w + dx; ld += (double)(dx * dx);
            orow[c4] = o;
        }
        if (tx == 0) out[IDX_OFF + t] = (float)w;
    }

    for (int off = 32; off; off >>= 1) ld += __shfl_down(ld, off);
    int lane = tid & 63, wvv = tid >> 6;
    if (lane == 0) lred[wvv] = ld;
    __syncthreads();
    if (tid == 0) {
        double s = (lred[0] + lred[1]) + (lred[2] + lred[3]);
        atomicAdd(loss_acc, s);
    }
}

// ---------------- kernel 3: finalize loss = fl(mf + fl(10*mf))
__global__ void vq_finish(const double* __restrict__ loss_acc, float* __restrict__ out)
{
#pragma clang fp contract(off)
    double m = *loss_acc / 16777216.0;
    float mf = (float)m;
    float second = 10.0f * mf;
    out[LOSS_OFF] = mf + second;
}

extern "C" void kernel_launch(void* const* d_in, const int* in_sizes, int n_in,
                              void* d_out, int out_size, void* d_ws, size_t ws_size,
                              hipStream_t stream)
{
    (void)in_sizes; (void)n_in; (void)out_size; (void)ws_size;
    const float* z  = (const float*)d_in[0];
    const float* cb = (const float*)d_in[1];
    float* out = (float*)d_out;
    double* loss_acc = (double*)d_ws;                                      // 8 B
    float* wsB = (float*)((char*)d_ws + 64);                               // 4 KB
    unsigned long long* keys = (unsigned long long*)((char*)d_ws + 8192);  // 512 KB
    float* wsA = (float*)((char*)d_ws + 532480);                           // 256 KB

    vq_prep<<<dim3(64), dim3(256), 0, stream>>>(cb, wsB, loss_acc, keys);
    vq_anorm<<<dim3(NTOK / 256), dim3(256), 0, stream>>>(z, wsA);
    vq_main<<<dim3(4096), dim3(512), 0, stream>>>(z, cb, wsB, wsA, keys);
    vq_gather<<<dim3(NTOK / 64), dim3(256), 0, stream>>>(z, cb, keys, loss_acc, out);
    vq_finish<<<dim3(1), dim3(1), 0, stream>>>(loss_acc, out);
}

// Round 13
// 617.819 us; speedup vs baseline: 2.2378x; 2.2378x over previous
//
#include <hip/hip_runtime.h>
#include <math.h>

// VQ quantizer: z [65536, 256] fp32, codebook [1024, 256] fp32.
// Outputs flat: z_q [16777216] | loss [1] | indices [65536] (as float values).
//
// Numerics contract (validated R1..R12, absmax 0.0 — keep bit-identical):
//   A_t = sum(z_t^2)  -- numpy pairwise order (8-acc chains, 128-blocks, fixed tree)
//   B_n = sum(e_n^2)  -- same
//   d   = fl( fl(A+B) - 2*M ),  M = fp32 fma-accumulated dot, k ascending
//   argmin: global first-min == lexicographic min of key (d_bits<<32 | idx)
//   z_q_out = fl( z + fl(e - z) ),  loss = fl(mf + fl(10*mf)), mf=(float)(Σdx²/2^24)
//
// R12 lesson: e-tile [code][32f] stride = 128 B = bank wrap -> all 64 lanes on
// one 4-bank group, 6.7e8 conflict cycles = the whole 1.1 ms regression.
// R13 = R12 + XOR swizzle of the 8 f4-blocks per code row (phys = ks ^ (code&7)),
// pre-swizzled global source (linear gload_lds dest) + same XOR on read:
// each 8-lane service group covers all 32 banks -> conflict-free b128.
// HARD RULE: never pass a 2nd __launch_bounds__ arg (VGPR=64 pin + GB spills).

#define NTOK     65536
#define DDIM     256
#define NCODE    1024
#define LOSS_OFF 16777216
#define IDX_OFF  16777217

// ws layout: [0] double loss_acc | [64] float wsB[1024] | [8192] u64 keys[65536]
//            | [532480] float wsA[65536]

#define GLOAD_LDS16(gp, lp)                                                       \
    __builtin_amdgcn_global_load_lds(                                             \
        (const __attribute__((address_space(1))) void*)(gp),                      \
        (__attribute__((address_space(3))) void*)(lp), 16, 0, 0)

// ---------------- kernel 0: B_n (numpy-pairwise), zero loss, init argmin keys.
__global__ void vq_prep(const float* __restrict__ cb, float* __restrict__ wsB,
                        double* __restrict__ loss_acc,
                        unsigned long long* __restrict__ keys)
{
#pragma clang fp contract(off)
    int gid = blockIdx.x * blockDim.x + threadIdx.x;
    if (gid == 0) *loss_acc = 0.0;
    unsigned long long* kp = keys + (size_t)gid * 4;
    kp[0] = kp[1] = kp[2] = kp[3] = 0xFFFFFFFFFFFFFFFFull;
    if (gid >= NCODE) return;
    const float* a = cb + gid * DDIM;
    float half[2];
    for (int h = 0; h < 2; ++h) {
        const float* b = a + h * 128;
        float r[8];
#pragma unroll
        for (int j = 0; j < 8; ++j) { float v = b[j]; r[j] = v * v; }
        for (int i = 8; i < 128; i += 8) {
#pragma unroll
            for (int j = 0; j < 8; ++j) { float v = b[i + j]; float s = v * v; r[j] = r[j] + s; }
        }
        half[h] = ((r[0] + r[1]) + (r[2] + r[3])) + ((r[4] + r[5]) + (r[6] + r[7]));
    }
    wsB[gid] = half[0] + half[1];
}

// ---------------- kernel 0b: A_t (numpy-pairwise) for every token.
__global__ void vq_anorm(const float* __restrict__ z, float* __restrict__ wsA)
{
#pragma clang fp contract(off)
    int t = blockIdx.x * blockDim.x + threadIdx.x;
    const float* a = z + (size_t)t * DDIM;
    float half[2];
    for (int h = 0; h < 2; ++h) {
        const float* b = a + h * 128;
        float r[8];
#pragma unroll
        for (int j = 0; j < 8; ++j) { float v = b[j]; r[j] = v * v; }
        for (int i = 8; i < 128; i += 8) {
#pragma unroll
            for (int j = 0; j < 8; ++j) { float v = b[i + j]; float s = v * v; r[j] = r[j] + s; }
        }
        half[h] = ((r[0] + r[1]) + (r[2] + r[3])) + ((r[4] + r[5]) + (r[6] + r[7]));
    }
    wsA[t] = half[0] + half[1];
}

// ---------------- kernel 1: distance GEMM + per-tile argmin -> atomicMin keys.
// Grid 4096 x 512: block b -> xcd = b&7, sl = b>>3, token-tile tt = xcd*64+(sl>>3),
// code-tile ct = sl&7 (siblings of a token-tile share one XCD's L2).
// Wave wv owns 16 tokens (z via wave-uniform SGPR loads); lane L owns codes
// {n0+L, n0+64+L} (e via lane-unique swizzled ds_read_b128 from a
// double-buffered [128 codes][32 k] LDS tile staged with global_load_lds).
__global__ __launch_bounds__(512) void vq_main(const float* __restrict__ z,
                                               const float* __restrict__ cb,
                                               const float* __restrict__ wsB,
                                               const float* __restrict__ wsA,
                                               unsigned long long* __restrict__ keys)
{
    __shared__ float es[2][128 * 32];   // 2 x 16 KB double buffer

    const int tid = threadIdx.x;
    const int L = tid & 63;
    const int wv = __builtin_amdgcn_readfirstlane(tid >> 6);   // 0..7, SGPR
    const int b = blockIdx.x;
    const int xcd = b & 7, sl = b >> 3;
    const int tt = xcd * 64 + (sl >> 3);
    const int ct = sl & 7;
    const int t0 = tt * 128;
    const int n0 = ct * 128;

    // wave-uniform z pointer: tokens t0+16*wv .. +15 (scalar-load path)
    const float* zw = z + (size_t)(t0 + 16 * wv) * DDIM;

    // per-lane codebook norms
    const float B0 = wsB[n0 + L];
    const float B1 = wsB[n0 + 64 + L];

    // staging (both-sides swizzle, rule 21): dest is LINEAR (lane L -> float idx
    // (wv*64+L)*4, i.e. code row wv*8+(L>>3), phys f4 = L&7); the SOURCE supplies
    // logical ks = phys ^ (row&7) = (L&7) ^ ((L>>3)&7).
    const char* cbc = (const char*)cb;
    const int swz = (L & 7) ^ ((L >> 3) & 7);
    const long eoffA = (long)(n0 + wv * 8 + (L >> 3)) * 1024 + swz * 16;
    const long eoffB = (long)(n0 + 64 + wv * 8 + (L >> 3)) * 1024 + swz * 16;

    float acc[16][2];
#pragma unroll
    for (int i = 0; i < 16; ++i) { acc[i][0] = 0.0f; acc[i][1] = 0.0f; }

    // prologue: stage kc=0 into buffer 0
    GLOAD_LDS16(cbc + eoffA, &es[0][wv * 256]);
    GLOAD_LDS16(cbc + eoffB, &es[0][2048 + wv * 256]);
    __syncthreads();

    const int sw = L & 7;   // read-side swizzle: phys f4 = ks ^ sw
    int cur = 0;
    for (int kc = 0; kc < 8; ++kc) {
        if (kc < 7) {   // prefetch next k-chunk into the other buffer
            GLOAD_LDS16(cbc + eoffA + (kc + 1) * 128, &es[cur ^ 1][wv * 256]);
            GLOAD_LDS16(cbc + eoffB + (kc + 1) * 128, &es[cur ^ 1][2048 + wv * 256]);
        }
        const float* ep0 = &es[cur][32 * L];          // code n0+L, 32 k-values
        const float* ep1 = &es[cur][2048 + 32 * L];   // code n0+64+L
#pragma unroll
        for (int ks = 0; ks < 8; ++ks) {
            const int p = (ks ^ sw) << 2;
            float4 ea = *(const float4*)(ep0 + p);
            float4 eb = *(const float4*)(ep1 + p);
            const float* zk = zw + (kc * 8 + ks) * 4;
#pragma unroll
            for (int tok = 0; tok < 16; ++tok) {
                float4 zf = *(const float4*)(zk + tok * 256);   // uniform -> s_load
                acc[tok][0] = __builtin_fmaf(zf.x, ea.x, acc[tok][0]);
                acc[tok][0] = __builtin_fmaf(zf.y, ea.y, acc[tok][0]);
                acc[tok][0] = __builtin_fmaf(zf.z, ea.z, acc[tok][0]);
                acc[tok][0] = __builtin_fmaf(zf.w, ea.w, acc[tok][0]);
                acc[tok][1] = __builtin_fmaf(zf.x, eb.x, acc[tok][1]);
                acc[tok][1] = __builtin_fmaf(zf.y, eb.y, acc[tok][1]);
                acc[tok][1] = __builtin_fmaf(zf.z, eb.z, acc[tok][1]);
                acc[tok][1] = __builtin_fmaf(zf.w, eb.w, acc[tok][1]);
            }
        }
        __syncthreads();   // drains prefetch vmcnt + all lanes done with cur
        cur ^= 1;
    }

    // epilogue: d = fl(fl(A+B) - 2*M); global first-min via 64-lane butterfly
    unsigned long long mykey = 0xFFFFFFFFFFFFFFFFull;
#pragma unroll
    for (int tok = 0; tok < 16; ++tok) {
        float A = wsA[t0 + 16 * wv + tok];            // uniform -> scalar load
        float t1a = A + B0;
        float dA = t1a - 2.0f * acc[tok][0];
        float t1b = A + B1;
        float dB = t1b - 2.0f * acc[tok][1];
        float d; int n;
        if (dB < dA) { d = dB; n = n0 + 64 + L; }     // strict: ties keep lower idx
        else         { d = dA; n = n0 + L; }
        for (int off = 1; off < 64; off <<= 1) {
            float od = __shfl_xor(d, off);
            int   on = __shfl_xor(n, off);
            if (od < d || (od == d && on < n)) { d = od; n = on; }
        }
        if (L == tok) mykey = ((unsigned long long)__float_as_uint(d) << 32) |
                              (unsigned int)n;
    }
    if (L < 16) atomicMin(&keys[t0 + 16 * wv + L], mykey);
}

// ---------------- kernel 2: gather z_q, indices, fp64 loss partials.
__global__ __launch_bounds__(256) void vq_gather(const float* __restrict__ z,
                                                 const float* __restrict__ cb,
                                                 const unsigned long long* __restrict__ keys,
                                                 double* __restrict__ loss_acc,
                                                 float* __restrict__ out)
{
    __shared__ double lred[4];
    const int tid = threadIdx.x;
    const int tx = tid & 15, ty = tid >> 4;
    const int t0 = blockIdx.x * 64;

    double ld = 0.0;
#pragma unroll
    for (int i = 0; i < 4; ++i) {
        int t = t0 + ty * 4 + i;
        unsigned long long key = keys[t];
        int w = (int)(unsigned int)(key & 0xFFFFFFFFull);
        const float4* crow = (const float4*)(cb + (size_t)w * DDIM);
        const float4* zrow = (const float4*)(z + (size_t)t * DDIM);
        float4* orow = (float4*)(out + (size_t)t * DDIM);
#pragma unroll
        for (int q = 0; q < 4; ++q) {
            int c4 = tx * 4 + q;
            float4 e4 = crow[c4];
            float4 z4 = zrow[c4];
            float4 o;
            float dx;
            dx = e4.x - z4.x; o.x = z4.x + dx; ld += (double)(dx * dx);
            dx = e4.y - z4.y; o.y = z4.y + dx; ld += (double)(dx * dx);
            dx = e4.z - z4.z; o.z = z4.z + dx; ld += (double)(dx * dx);
            dx = e4.w - z4.w; o.w = z4.w + dx; ld += (double)(dx * dx);
            orow[c4] = o;
        }
        if (tx == 0) out[IDX_OFF + t] = (float)w;
    }

    for (int off = 32; off; off >>= 1) ld += __shfl_down(ld, off);
    int lane = tid & 63, wvv = tid >> 6;
    if (lane == 0) lred[wvv] = ld;
    __syncthreads();
    if (tid == 0) {
        double s = (lred[0] + lred[1]) + (lred[2] + lred[3]);
        atomicAdd(loss_acc, s);
    }
}

// ---------------- kernel 3: finalize loss = fl(mf + fl(10*mf))
__global__ void vq_finish(const double* __restrict__ loss_acc, float* __restrict__ out)
{
#pragma clang fp contract(off)
    double m = *loss_acc / 16777216.0;
    float mf = (float)m;
    float second = 10.0f * mf;
    out[LOSS_OFF] = mf + second;
}

extern "C" void kernel_launch(void* const* d_in, const int* in_sizes, int n_in,
                              void* d_out, int out_size, void* d_ws, size_t ws_size,
                              hipStream_t stream)
{
    (void)in_sizes; (void)n_in; (void)out_size; (void)ws_size;
    const float* z  = (const float*)d_in[0];
    const float* cb = (const float*)d_in[1];
    float* out = (float*)d_out;
    double* loss_acc = (double*)d_ws;                                      // 8 B
    float* wsB = (float*)((char*)d_ws + 64);                               // 4 KB
    unsigned long long* keys = (unsigned long long*)((char*)d_ws + 8192);  // 512 KB
    float* wsA = (float*)((char*)d_ws + 532480);                           // 256 KB

    vq_prep<<<dim3(64), dim3(256), 0, stream>>>(cb, wsB, loss_acc, keys);
    vq_anorm<<<dim3(NTOK / 256), dim3(256), 0, stream>>>(z, wsA);
    vq_main<<<dim3(4096), dim3(512), 0, stream>>>(z, cb, wsB, wsA, keys);
    vq_gather<<<dim3(NTOK / 64), dim3(256), 0, stream>>>(z, cb, keys, loss_acc, out);
    vq_finish<<<dim3(1), dim3(1), 0, stream>>>(loss_acc, out);
}